// Round 8
// baseline (995.878 us; speedup 1.0000x reference)
//
#include <hip/hip_runtime.h>
#include <math.h>

// Problem dims
#define Dd 256
#define Hh 512
#define Rr 16
#define Ss 16
#define Bb 4
#define Ll 2048
#define BLrows (Bb*Ll)            // 8192
#define EPSf 1e-5f
#define RSQ1PEPS 0.99999500003749963f   // 1/sqrt(1+1e-5)

// ws layout (float offsets), lifetime-overlapped. Peak = 16777216 floats = 64 MB.
// z lives in d_out (2M floats, dead before out is written at step 16).
// arena map (1M = 1048576 floats):
//   l0:0-2  h0:2-4  cat:4-10(catl then cath)  lh:10-14
//   t:4-8(over cat)  cc:0-2(over l0)  ctxn:2-4(over h0)
//   zu:4-8(over t; u1 in-place)  zv:8-12(over cat tail/lh head; vg in-place)
//   u:12-16(over lh tail)  zc:0-0.4(over cc)  dt:4-8(over u1)  y:4-8(=dt, in-place)
#define OFF_L0    0u
#define OFF_H0    2097152u
#define OFF_CAT   4194304u
#define OFF_LH    10485760u
#define OFF_T     4194304u
#define OFF_CC    0u
#define OFF_CTXN  2097152u
#define OFF_ZU    4194304u
#define OFF_ZV    8388608u
#define OFF_U     12582912u
#define OFF_ZC    0u
#define OFF_DT    4194304u
#define OFF_Y     4194304u   /* in-place over dt (proven safe: per-(row,h) single owner) */
#define WS_NEED_BYTES (16777216ull*4ull)

__device__ __forceinline__ float sigmoidf_(float x){ return 1.0f/(1.0f+expf(-x)); }
__device__ __forceinline__ float siluf_(float x){ return x/(1.0f+expf(-x)); }
__device__ __forceinline__ float softplusf_(float x){
  if (x > 30.0f) return x;
  return log1pf(expf(x));
}

// ---------------- LN over D=256, one wave per row, 4 rows/block ----------------
__global__ __launch_bounds__(256)
void k_ln1(const float* __restrict__ x, const float* __restrict__ g,
           const float* __restrict__ b, float* __restrict__ z)
{
  const int row  = blockIdx.x*4 + (threadIdx.x>>6);
  const int lane = threadIdx.x & 63;
  const float* xr = x + (size_t)row*Dd + lane*4;
  float4 v = *(const float4*)xr;
  float s  = v.x+v.y+v.z+v.w;
  float sq = v.x*v.x+v.y*v.y+v.z*v.z+v.w*v.w;
  #pragma unroll
  for (int d=32; d; d>>=1){ s += __shfl_xor(s,d,64); sq += __shfl_xor(sq,d,64); }
  const float m   = s  * (1.0f/Dd);
  const float var = sq * (1.0f/Dd) - m*m;
  const float r   = 1.0f/sqrtf(var + EPSf);
  float4 gg = *(const float4*)(g + lane*4);
  float4 bb = *(const float4*)(b + lane*4);
  float4 o;
  o.x = (v.x-m)*r*gg.x + bb.x;
  o.y = (v.y-m)*r*gg.y + bb.y;
  o.z = (v.z-m)*r*gg.z + bb.z;
  o.w = (v.w-m)*r*gg.w + bb.w;
  *(float4*)(z + (size_t)row*Dd + lane*4) = o;
}

// ---------------- double LN (fln then gln) ----------------
__global__ __launch_bounds__(256)
void k_dln(const float* __restrict__ cc,
           const float* __restrict__ fg, const float* __restrict__ fb,
           const float* __restrict__ gg_, const float* __restrict__ gb_,
           float* __restrict__ ctxn)
{
  const int row  = blockIdx.x*4 + (threadIdx.x>>6);
  const int lane = threadIdx.x & 63;
  float4 v = *(const float4*)(cc + (size_t)row*Dd + lane*4);
  float s  = v.x+v.y+v.z+v.w;
  float sq = v.x*v.x+v.y*v.y+v.z*v.z+v.w*v.w;
  #pragma unroll
  for (int d=32; d; d>>=1){ s += __shfl_xor(s,d,64); sq += __shfl_xor(sq,d,64); }
  float m   = s*(1.0f/Dd);
  float var = sq*(1.0f/Dd) - m*m;
  float r   = 1.0f/sqrtf(var + EPSf);
  float4 g1 = *(const float4*)(fg + lane*4);
  float4 b1 = *(const float4*)(fb + lane*4);
  float4 w;
  w.x = (v.x-m)*r*g1.x + b1.x;
  w.y = (v.y-m)*r*g1.y + b1.y;
  w.z = (v.z-m)*r*g1.z + b1.z;
  w.w = (v.w-m)*r*g1.w + b1.w;
  s  = w.x+w.y+w.z+w.w;
  sq = w.x*w.x+w.y*w.y+w.z*w.z+w.w*w.w;
  #pragma unroll
  for (int d=32; d; d>>=1){ s += __shfl_xor(s,d,64); sq += __shfl_xor(sq,d,64); }
  m   = s*(1.0f/Dd);
  var = sq*(1.0f/Dd) - m*m;
  r   = 1.0f/sqrtf(var + EPSf);
  float4 g2 = *(const float4*)(gg_ + lane*4);
  float4 b2 = *(const float4*)(gb_ + lane*4);
  float4 o;
  o.x = (w.x-m)*r*g2.x + b2.x;
  o.y = (w.y-m)*r*g2.y + b2.y;
  o.z = (w.z-m)*r*g2.z + b2.z;
  o.w = (w.w-m)*r*g2.w + b2.w;
  *(float4*)(ctxn + (size_t)row*Dd + lane*4) = o;
}

// ---------------- moving-average 9 + highpass split ----------------
__global__ __launch_bounds__(256)
void k_avg(const float* __restrict__ z, const float* __restrict__ favg,
           float* __restrict__ l0, float* __restrict__ h0)
{
  const int idx = blockIdx.x*256 + threadIdx.x;   // over B*L*D
  const int d  = idx & (Dd-1);
  const int bl = idx >> 8;
  const int l  = bl & (Ll-1);
  float acc = 0.0f;
  #pragma unroll
  for (int k=0;k<9;k++){
    const int ll = l + k - 4;
    const float zv = (ll>=0 && ll<Ll) ? z[(size_t)(bl+k-4)*Dd + d] : 0.0f;
    acc = fmaf(favg[d*9+k], zv, acc);
  }
  const float zv0 = z[(size_t)bl*Dd + d];
  l0[idx] = acc;
  h0[idx] = zv0 - acc;
}

// ---------------- 3 lowpass depthwise convs -> cat (as catl) ----------------
__global__ __launch_bounds__(256)
void k_convl(const float* __restrict__ l0,
             const float* __restrict__ w5, const float* __restrict__ w9,
             const float* __restrict__ w13, float* __restrict__ cat)
{
  const int idx = blockIdx.x*256 + threadIdx.x;
  const int d  = idx & (Dd-1);
  const int bl = idx >> 8;
  const int l  = bl & (Ll-1);
  float lw[13];
  #pragma unroll
  for (int o=0;o<13;o++){
    const int ll = l + o - 6;
    lw[o] = (ll>=0 && ll<Ll) ? l0[(size_t)(bl+o-6)*Dd + d] : 0.0f;
  }
  float a5=0.f, a9=0.f, a13=0.f;
  #pragma unroll
  for (int k=0;k<5;k++)  a5  = fmaf(w5 [d*5+k],  lw[k+4], a5);
  #pragma unroll
  for (int k=0;k<9;k++)  a9  = fmaf(w9 [d*9+k],  lw[k+2], a9);
  #pragma unroll
  for (int k=0;k<13;k++) a13 = fmaf(w13[d*13+k], lw[k],   a13);
  float* cl = cat + (size_t)bl*768;
  cl[d] = a5;  cl[256+d] = a9;  cl[512+d] = a13;
}

// ---------------- 3 highpass depthwise convs -> cat (as cath) ----------------
__global__ __launch_bounds__(256)
void k_convh(const float* __restrict__ h0,
             const float* __restrict__ w3, const float* __restrict__ wh5,
             const float* __restrict__ w7, float* __restrict__ cat)
{
  const int idx = blockIdx.x*256 + threadIdx.x;
  const int d  = idx & (Dd-1);
  const int bl = idx >> 8;
  const int l  = bl & (Ll-1);
  float hw[7];
  #pragma unroll
  for (int o=0;o<7;o++){
    const int ll = l + o - 3;
    hw[o] = (ll>=0 && ll<Ll) ? h0[(size_t)(bl+o-3)*Dd + d] : 0.0f;
  }
  float c3=0.f, c5=0.f, c7=0.f;
  #pragma unroll
  for (int k=0;k<3;k++)  c3  = fmaf(w3 [d*3+k],  hw[k+2], c3);
  #pragma unroll
  for (int k=0;k<5;k++)  c5  = fmaf(wh5[d*5+k],  hw[k+1], c5);
  #pragma unroll
  for (int k=0;k<7;k++)  c7  = fmaf(w7 [d*7+k],  hw[k],   c7);
  float* ch = cat + (size_t)bl*768;
  ch[d] = c3;  ch[256+d] = c5;  ch[512+d] = c7;
}

// ---------------- causal conv3 + bias + silu on u1 ----------------
__global__ __launch_bounds__(256)
void k_cconv(const float* __restrict__ u1, const float* __restrict__ xbw,
             const float* __restrict__ xbb, float* __restrict__ u)
{
  const int idx = blockIdx.x*256 + threadIdx.x;  // over B*L*H
  const int h  = idx & (Hh-1);
  const int bl = idx >> 9;
  const int l  = bl & (Ll-1);
  float acc = xbb[h];
  #pragma unroll
  for (int k=0;k<3;k++){
    const int ll = l - 2 + k;
    if (ll >= 0) acc = fmaf(xbw[h*3+k], u1[(size_t)(bl-2+k)*Hh + h], acc);
  }
  u[idx] = siluf_(acc);
}

// ---------------- tiled fp32 GEMM: C = epi(A @ W^T) ----------------
// A: (M,lda) row-major using K cols; W: (N,K) row-major.
// 64x64 tile, BK=16, 128 threads, 8x4 microtile, reg prefetch of next K-slab.
template<int EPI>
__global__ __launch_bounds__(128)
void k_gemm(const int M, const int N, const int K, const int lda,
            const float* __restrict__ A, const float* __restrict__ W,
            float* __restrict__ C, const int ldc,
            const float* __restrict__ e0, const float* __restrict__ e1,
            const float* __restrict__ e2, const int lde)
{
  __shared__ float As[16][68];
  __shared__ float Bs[16][68];
  const int tid = threadIdx.x;
  const int bm = blockIdx.x << 6;
  const int bn = blockIdx.y << 6;
  const int tx = tid & 15;          // n quad (4 cols)
  const int ty = tid >> 4;          // m oct  (8 rows), 0..7
  const int srow = tid >> 1;        // staging row 0..63
  const int scol = (tid & 1) << 3;  // staging col 0 or 8

  const float* Aptr = A + (size_t)(bm + srow)*lda + scol;
  const bool bok = (bn + srow) < N;
  const float* Wptr = W + (size_t)(bn + srow)*K + scol;

  float4 a0 = *(const float4*)(Aptr);
  float4 a1 = *(const float4*)(Aptr + 4);
  float4 w0 = make_float4(0.f,0.f,0.f,0.f), w1 = w0;
  if (bok){ w0 = *(const float4*)(Wptr); w1 = *(const float4*)(Wptr + 4); }

  float acc[8][4];
  #pragma unroll
  for (int i=0;i<8;i++)
    #pragma unroll
    for (int j=0;j<4;j++) acc[i][j]=0.0f;

  for (int k0 = 0; k0 < K; k0 += 16){
    __syncthreads();
    As[scol+0][srow]=a0.x; As[scol+1][srow]=a0.y; As[scol+2][srow]=a0.z; As[scol+3][srow]=a0.w;
    As[scol+4][srow]=a1.x; As[scol+5][srow]=a1.y; As[scol+6][srow]=a1.z; As[scol+7][srow]=a1.w;
    Bs[scol+0][srow]=w0.x; Bs[scol+1][srow]=w0.y; Bs[scol+2][srow]=w0.z; Bs[scol+3][srow]=w0.w;
    Bs[scol+4][srow]=w1.x; Bs[scol+5][srow]=w1.y; Bs[scol+6][srow]=w1.z; Bs[scol+7][srow]=w1.w;
    __syncthreads();
    if (k0 + 16 < K){                       // prefetch next slab into regs
      a0 = *(const float4*)(Aptr + k0 + 16);
      a1 = *(const float4*)(Aptr + k0 + 20);
      if (bok){
        w0 = *(const float4*)(Wptr + k0 + 16);
        w1 = *(const float4*)(Wptr + k0 + 20);
      }
    }
    #pragma unroll
    for (int kk=0;kk<16;kk++){
      const float4 b4 = *(const float4*)&Bs[kk][tx<<2];
      const float4 aA = *(const float4*)&As[kk][ty<<3];
      const float4 aB = *(const float4*)&As[kk][(ty<<3)+4];
      const float ar[8] = {aA.x,aA.y,aA.z,aA.w,aB.x,aB.y,aB.z,aB.w};
      const float br[4] = {b4.x,b4.y,b4.z,b4.w};
      #pragma unroll
      for (int i=0;i<8;i++)
        #pragma unroll
        for (int j=0;j<4;j++) acc[i][j] = fmaf(ar[i], br[j], acc[i][j]);
    }
  }

  const int col0 = bn + (tx<<2);
  const bool full = (col0 + 3) < N;
  #pragma unroll
  for (int i=0;i<8;i++){
    const int row = bm + (ty<<3) + i;
    float r[4];
    #pragma unroll
    for (int j=0;j<4;j++){
      const int col = col0 + j;
      const float v = acc[i][j];
      float rr;
      if constexpr (EPI==0)      rr = v;                                   // none (xc)
      else if constexpr (EPI==1) rr = v + e0[col];                         // +bias (xa halves)
      else if constexpr (EPI==2) rr = siluf_(v*(e0[col]*RSQ1PEPS) + e1[col])
                                     + e2[(size_t)row*lde + col];          // fd/fe
      else if constexpr (EPI==3) rr = siluf_(v*(e0[col]*RSQ1PEPS) + e1[col]); // ff1
      else if constexpr (EPI==4) rr = v + 0.5f*(e0[(size_t)row*lde + col]
                                     + e0[(size_t)row*lde + col + 256]);   // ff2 + rr
      else if constexpr (EPI==5) rr = e1[(size_t)row*lde + col]
                                     * (1.0f + sigmoidf_(v + e0[col]));    // gb -> u1 (in-place over e1)
      else if constexpr (EPI==6) rr = e1[(size_t)row*lde + col] + v + e0[col]; // gc -> vg (in-place over e1)
      else if constexpr (EPI==7) rr = softplusf_(v + e0[col]);             // xe -> dt
      else                       rr = v + e0[col] + e1[(size_t)row*lde + col]; // xi (+x)
      r[j] = rr;
    }
    if (full){
      *(float4*)&C[(size_t)row*ldc + col0] = make_float4(r[0],r[1],r[2],r[3]);
    } else {
      #pragma unroll
      for (int j=0;j<4;j++)
        if (col0 + j < N) C[(size_t)row*ldc + col0 + j] = r[j];
    }
  }
}

// ---------------- SSM scan: one wave per (b,h) chain ----------------
__global__ __launch_bounds__(256)
void k_scan(const float* __restrict__ dt, const float* __restrict__ u,
            const float* __restrict__ zc, const float* __restrict__ xf,
            const float* __restrict__ xg, const float* __restrict__ vg,
            float* __restrict__ y)
{
  const int wid  = blockIdx.x*4 + (threadIdx.x>>6);  // 0..2047
  const int lane = threadIdx.x & 63;
  const int b = wid >> 9;
  const int h = wid & (Hh-1);
  float a[16];
  #pragma unroll
  for (int s=0;s<16;s++) a[s] = -expf(xf[h*16+s]);
  const int CH = Ll/64;                 // 32
  const size_t rowbase = (size_t)b*Ll + lane*CH;
  float P[16], st[16];
  #pragma unroll
  for (int s=0;s<16;s++){ P[s]=1.0f; st[s]=0.0f; }
  // pass 1: local segment transform (P = prod aa, st = local final state from 0)
  for (int j=0;j<CH;j++){
    const size_t row = rowbase + j;
    const float dtv = dt[row*Hh + h];
    const float uv  = u [row*Hh + h];
    const float du  = dtv*uv;
    const float* z48 = zc + row*48;
    #pragma unroll
    for (int s=0;s<16;s++){
      const float aa = expf(dtv*a[s]);
      st[s] = fmaf(aa, st[s], du*z48[16+s]);
      P[s] *= aa;
    }
  }
  // inclusive wave scan of (P, st) under composition (A2*A1, A2*B1+B2)
  #pragma unroll
  for (int dd=1; dd<64; dd<<=1){
    #pragma unroll
    for (int s=0;s<16;s++){
      const float Po = __shfl_up(P[s],  dd, 64);
      const float Bo = __shfl_up(st[s], dd, 64);
      if (lane >= dd){ st[s] = fmaf(P[s], Bo, st[s]); P[s] *= Po; }
    }
  }
  // exclusive -> per-lane initial state
  float init[16];
  #pragma unroll
  for (int s=0;s<16;s++){
    const float e = __shfl_up(st[s], 1, 64);
    init[s] = (lane==0) ? 0.0f : e;
  }
  const float xgh = xg[h];
  #pragma unroll
  for (int s=0;s<16;s++) st[s] = init[s];
  // pass 2: rescan with correct init, emit outputs (y may alias dt: per-(row,h)
  // element is owned by exactly one lane; read precedes write in that lane)
  for (int j=0;j<CH;j++){
    const size_t row = rowbase + j;
    const float dtv = dt[row*Hh + h];
    const float uv  = u [row*Hh + h];
    const float du  = dtv*uv;
    const float* z48 = zc + row*48;
    float ys = 0.0f;
    #pragma unroll
    for (int s=0;s<16;s++){
      const float aa = expf(dtv*a[s]);
      st[s] = fmaf(aa, st[s], du*z48[16+s]);
      ys = fmaf(st[s], z48[32+s], ys);
    }
    const float vgv = vg[row*Hh + h];
    const float yv = (ys + uv*xgh) * (vgv / (1.0f + expf(-vgv)));
    y[row*Hh + h] = yv;
  }
}

extern "C" void kernel_launch(void* const* d_in, const int* in_sizes, int n_in,
                              void* d_out, int out_size, void* d_ws, size_t ws_size,
                              hipStream_t stream)
{
  const float* x      = (const float*)d_in[0];
  const float* ln1_g  = (const float*)d_in[1];
  const float* ln1_b  = (const float*)d_in[2];
  const float* favg_w = (const float*)d_in[3];
  const float* lk5_w  = (const float*)d_in[4];
  const float* lk9_w  = (const float*)d_in[5];
  const float* lk13_w = (const float*)d_in[6];
  const float* hk3_w  = (const float*)d_in[7];
  const float* hk5_w  = (const float*)d_in[8];
  const float* hk7_w  = (const float*)d_in[9];
  const float* fd_w   = (const float*)d_in[10];
  const float* fd_bn_g= (const float*)d_in[11];
  const float* fd_bn_b= (const float*)d_in[12];
  const float* fe_w   = (const float*)d_in[13];
  const float* fe_bn_g= (const float*)d_in[14];
  const float* fe_bn_b= (const float*)d_in[15];
  const float* ff1_w  = (const float*)d_in[16];
  const float* ff_bn_g= (const float*)d_in[17];
  const float* ff_bn_b= (const float*)d_in[18];
  const float* ff2_w  = (const float*)d_in[19];
  const float* fln_g  = (const float*)d_in[20];
  const float* fln_b  = (const float*)d_in[21];
  const float* xa_w   = (const float*)d_in[22];
  const float* xa_b   = (const float*)d_in[23];
  const float* xb_w   = (const float*)d_in[24];
  const float* xb_b   = (const float*)d_in[25];
  const float* xc_w   = (const float*)d_in[26];
  const float* xe_w   = (const float*)d_in[27];
  const float* xe_b   = (const float*)d_in[28];
  const float* xf     = (const float*)d_in[29];
  const float* xg     = (const float*)d_in[30];
  const float* xi_w   = (const float*)d_in[31];
  const float* xi_b   = (const float*)d_in[32];
  const float* gln_g  = (const float*)d_in[33];
  const float* gln_b  = (const float*)d_in[34];
  const float* gb_w   = (const float*)d_in[35];
  const float* gb_b   = (const float*)d_in[36];
  const float* gc_w   = (const float*)d_in[37];
  const float* gc_b   = (const float*)d_in[38];
  float* out = (float*)d_out;

  // OOB guard: if the harness workspace is smaller than our arena, do nothing.
  // (Clean "incorrect" beats a container-killing memory fault, and the error
  //  mode itself tells us ws_size < 64MB.)
  if (ws_size < WS_NEED_BYTES) return;

  float* ws = (float*)d_ws;
  float* z    = out;              // d_out doubles as z-scratch (dead before step 16)
  float* l0   = ws + OFF_L0;
  float* h0   = ws + OFF_H0;
  float* cat  = ws + OFF_CAT;
  float* lh   = ws + OFF_LH;
  float* t    = ws + OFF_T;
  float* cc   = ws + OFF_CC;
  float* ctxn = ws + OFF_CTXN;
  float* zu   = ws + OFF_ZU;      // u-half of zz; u1 in-place
  float* zv   = ws + OFF_ZV;      // v-half of zz; vg in-place
  float* u    = ws + OFF_U;
  float* zcb  = ws + OFF_ZC;
  float* dt   = ws + OFF_DT;
  float* y    = ws + OFF_Y;       // in-place over dt

  const dim3 thr(256);
  const dim3 gthr(128);

  // 1) z = LN(x)   (z lives in d_out)
  k_ln1<<<dim3(BLrows/4), thr, 0, stream>>>(x, ln1_g, ln1_b, z);
  // 2) l0 = avg9(z), h0 = z - l0
  k_avg<<<dim3(BLrows*Dd/256), thr, 0, stream>>>(z, favg_w, l0, h0);
  // 3a) lowpass convs -> cat (catl)
  k_convl<<<dim3(BLrows*Dd/256), thr, 0, stream>>>(l0, lk5_w, lk9_w, lk13_w, cat);
  // 4) l1 = silu(bn(catl@fd^T)) + l0  -> lh[:, :256]
  k_gemm<2><<<dim3(128,4), gthr, 0, stream>>>(BLrows,256,768,768, cat, fd_w,
                                              lh, 512, fd_bn_g, fd_bn_b, l0, 256);
  // 3b) highpass convs -> cat (cath; catl dead after step 4)
  k_convh<<<dim3(BLrows*Dd/256), thr, 0, stream>>>(h0, hk3_w, hk5_w, hk7_w, cat);
  // 5) h1 -> lh[:, 256:]
  k_gemm<2><<<dim3(128,4), gthr, 0, stream>>>(BLrows,256,768,768, cat, fe_w,
                                              lh+256, 512, fe_bn_g, fe_bn_b, h0, 256);
  // 6) t = silu(bn(lh@ff1^T))
  k_gemm<3><<<dim3(128,8), gthr, 0, stream>>>(BLrows,512,512,512, lh, ff1_w,
                                              t, 512, ff_bn_g, ff_bn_b, nullptr, 0);
  // 7) cc = t@ff2^T + 0.5*(l1+h1)
  k_gemm<4><<<dim3(128,4), gthr, 0, stream>>>(BLrows,256,512,512, t, ff2_w,
                                              cc, 256, lh, nullptr, nullptr, 512);
  // 8) ctxn = LN(LN(cc, fln), gln)
  k_dln<<<dim3(BLrows/4), thr, 0, stream>>>(cc, fln_g, fln_b, gln_g, gln_b, ctxn);
  // 9a) zu = z@xa_w[:512]^T + xa_b[:512]
  k_gemm<1><<<dim3(128,8), gthr, 0, stream>>>(BLrows,512,256,256, z, xa_w,
                                              zu, 512, xa_b, nullptr, nullptr, 0);
  // 9b) zv = z@xa_w[512:]^T + xa_b[512:]
  k_gemm<1><<<dim3(128,8), gthr, 0, stream>>>(BLrows,512,256,256, z, xa_w + 512*256,
                                              zv, 512, xa_b + 512, nullptr, nullptr, 0);
  // 10) u1 = zu * (1 + sigmoid(ctxn@gb^T + gb_b))   [in-place over zu]
  k_gemm<5><<<dim3(128,8), gthr, 0, stream>>>(BLrows,512,256,256, ctxn, gb_w,
                                              zu, 512, gb_b, zu, nullptr, 512);
  // 11) vg = zv + ctxn@gc^T + gc_b                  [in-place over zv]
  k_gemm<6><<<dim3(128,8), gthr, 0, stream>>>(BLrows,512,256,256, ctxn, gc_w,
                                              zv, 512, gc_b, zv, nullptr, 512);
  // 12) u = silu(causal_conv3(u1) + xb_b)
  k_cconv<<<dim3(BLrows*Hh/256), thr, 0, stream>>>(zu, xb_w, xb_b, u);
  // 13) zc = u@xc^T   (N=48)
  k_gemm<0><<<dim3(128,1), gthr, 0, stream>>>(BLrows,48,512,512, u, xc_w,
                                              zcb, 48, nullptr, nullptr, nullptr, 0);
  // 14) dt = softplus(zc[:, :16]@xe^T + xe_b)
  k_gemm<7><<<dim3(128,8), gthr, 0, stream>>>(BLrows,512,16,48, zcb, xe_w,
                                              dt, 512, xe_b, nullptr, nullptr, 0);
  // 15) scan -> y = (ys + u*xg) * silu(vg)          [y in-place over dt]
  k_scan<<<dim3(512), thr, 0, stream>>>(dt, u, zcb, xf, xg, zv, y);
  // 16) out = y@xi^T + xi_b + x
  k_gemm<8><<<dim3(128,4), gthr, 0, stream>>>(BLrows,256,512,512, y, xi_w,
                                              out, 256, xi_b, x, nullptr, 256);
}

// Round 9
// 712.738 us; speedup vs baseline: 1.3973x; 1.3973x over previous
//
#include <hip/hip_runtime.h>
#include <math.h>

// Problem dims
#define Dd 256
#define Hh 512
#define Rr 16
#define Ss 16
#define Bb 4
#define Ll 2048
#define BLrows (Bb*Ll)            // 8192
#define EPSf 1e-5f
#define RSQ1PEPS 0.99999500003749963f   // 1/sqrt(1+1e-5)

// fp32 ws arena (float offsets), lifetime-overlapped. 16M floats = 64 MB.
#define OFF_L0    0u
#define OFF_H0    2097152u
#define OFF_CAT   4194304u
#define OFF_LH    10485760u
#define OFF_T     4194304u
#define OFF_CC    0u
#define OFF_CTXN  2097152u
#define OFF_ZU    4194304u
#define OFF_ZV    8388608u
#define OFF_U     12582912u
#define OFF_ZC    0u
#define OFF_DT    4194304u
#define OFF_Y     4194304u
#define WS_NEED_BYTES (16777216ull*4ull)
// bf16 plane arena lives above the fp32 arena (bf16-unit offsets from bfp):
//  pfd 0  pfe 393216  pff1 786432  pff2 1310720  pxa 1572864
//  pgb 2097152  pgc 2359296  pxi 2621440  pact 2883584 (2*6291456)
#define WS_NEED2_BYTES (16777216ull*4ull + 15466496ull*2ull)   // 98,041,856

__device__ __forceinline__ float sigmoidf_(float x){ return 1.0f/(1.0f+expf(-x)); }
__device__ __forceinline__ float siluf_(float x){ return x/(1.0f+expf(-x)); }
__device__ __forceinline__ float softplusf_(float x){
  if (x > 30.0f) return x;
  return log1pf(expf(x));
}
__device__ __forceinline__ unsigned short f2bf(float x){
  unsigned int u = __float_as_uint(x);
  unsigned int r = (u + 0x7FFFu + ((u>>16)&1u)) >> 16;
  return (unsigned short)r;
}
__device__ __forceinline__ float bf2f(unsigned short h){
  return __uint_as_float(((unsigned int)h)<<16);
}

typedef __attribute__((ext_vector_type(8))) short bf8_t;   // 8 bf16 (4 VGPRs)
typedef __attribute__((ext_vector_type(4))) float f4_t;    // MFMA acc

// ---------------- LN over D=256, one wave per row, 4 rows/block ----------------
__global__ __launch_bounds__(256)
void k_ln1(const float* __restrict__ x, const float* __restrict__ g,
           const float* __restrict__ b, float* __restrict__ z)
{
  const int row  = blockIdx.x*4 + (threadIdx.x>>6);
  const int lane = threadIdx.x & 63;
  const float* xr = x + (size_t)row*Dd + lane*4;
  float4 v = *(const float4*)xr;
  float s  = v.x+v.y+v.z+v.w;
  float sq = v.x*v.x+v.y*v.y+v.z*v.z+v.w*v.w;
  #pragma unroll
  for (int d=32; d; d>>=1){ s += __shfl_xor(s,d,64); sq += __shfl_xor(sq,d,64); }
  const float m   = s  * (1.0f/Dd);
  const float var = sq * (1.0f/Dd) - m*m;
  const float r   = 1.0f/sqrtf(var + EPSf);
  float4 gg = *(const float4*)(g + lane*4);
  float4 bb = *(const float4*)(b + lane*4);
  float4 o;
  o.x = (v.x-m)*r*gg.x + bb.x;
  o.y = (v.y-m)*r*gg.y + bb.y;
  o.z = (v.z-m)*r*gg.z + bb.z;
  o.w = (v.w-m)*r*gg.w + bb.w;
  *(float4*)(z + (size_t)row*Dd + lane*4) = o;
}

// ---------------- double LN (fln then gln) ----------------
__global__ __launch_bounds__(256)
void k_dln(const float* __restrict__ cc,
           const float* __restrict__ fg, const float* __restrict__ fb,
           const float* __restrict__ gg_, const float* __restrict__ gb_,
           float* __restrict__ ctxn)
{
  const int row  = blockIdx.x*4 + (threadIdx.x>>6);
  const int lane = threadIdx.x & 63;
  float4 v = *(const float4*)(cc + (size_t)row*Dd + lane*4);
  float s  = v.x+v.y+v.z+v.w;
  float sq = v.x*v.x+v.y*v.y+v.z*v.z+v.w*v.w;
  #pragma unroll
  for (int d=32; d; d>>=1){ s += __shfl_xor(s,d,64); sq += __shfl_xor(sq,d,64); }
  float m   = s*(1.0f/Dd);
  float var = sq*(1.0f/Dd) - m*m;
  float r   = 1.0f/sqrtf(var + EPSf);
  float4 g1 = *(const float4*)(fg + lane*4);
  float4 b1 = *(const float4*)(fb + lane*4);
  float4 w;
  w.x = (v.x-m)*r*g1.x + b1.x;
  w.y = (v.y-m)*r*g1.y + b1.y;
  w.z = (v.z-m)*r*g1.z + b1.z;
  w.w = (v.w-m)*r*g1.w + b1.w;
  s  = w.x+w.y+w.z+w.w;
  sq = w.x*w.x+w.y*w.y+w.z*w.z+w.w*w.w;
  #pragma unroll
  for (int d=32; d; d>>=1){ s += __shfl_xor(s,d,64); sq += __shfl_xor(sq,d,64); }
  m   = s*(1.0f/Dd);
  var = sq*(1.0f/Dd) - m*m;
  r   = 1.0f/sqrtf(var + EPSf);
  float4 g2 = *(const float4*)(gg_ + lane*4);
  float4 b2 = *(const float4*)(gb_ + lane*4);
  float4 o;
  o.x = (w.x-m)*r*g2.x + b2.x;
  o.y = (w.y-m)*r*g2.y + b2.y;
  o.z = (w.z-m)*r*g2.z + b2.z;
  o.w = (w.w-m)*r*g2.w + b2.w;
  *(float4*)(ctxn + (size_t)row*Dd + lane*4) = o;
}

// ---------------- moving-average 9 + highpass split ----------------
__global__ __launch_bounds__(256)
void k_avg(const float* __restrict__ z, const float* __restrict__ favg,
           float* __restrict__ l0, float* __restrict__ h0)
{
  const int idx = blockIdx.x*256 + threadIdx.x;   // over B*L*D
  const int d  = idx & (Dd-1);
  const int bl = idx >> 8;
  const int l  = bl & (Ll-1);
  float acc = 0.0f;
  #pragma unroll
  for (int k=0;k<9;k++){
    const int ll = l + k - 4;
    const float zv = (ll>=0 && ll<Ll) ? z[(size_t)(bl+k-4)*Dd + d] : 0.0f;
    acc = fmaf(favg[d*9+k], zv, acc);
  }
  const float zv0 = z[(size_t)bl*Dd + d];
  l0[idx] = acc;
  h0[idx] = zv0 - acc;
}

// ---------------- 3 lowpass depthwise convs -> cat (as catl) ----------------
__global__ __launch_bounds__(256)
void k_convl(const float* __restrict__ l0,
             const float* __restrict__ w5, const float* __restrict__ w9,
             const float* __restrict__ w13, float* __restrict__ cat)
{
  const int idx = blockIdx.x*256 + threadIdx.x;
  const int d  = idx & (Dd-1);
  const int bl = idx >> 8;
  const int l  = bl & (Ll-1);
  float lw[13];
  #pragma unroll
  for (int o=0;o<13;o++){
    const int ll = l + o - 6;
    lw[o] = (ll>=0 && ll<Ll) ? l0[(size_t)(bl+o-6)*Dd + d] : 0.0f;
  }
  float a5=0.f, a9=0.f, a13=0.f;
  #pragma unroll
  for (int k=0;k<5;k++)  a5  = fmaf(w5 [d*5+k],  lw[k+4], a5);
  #pragma unroll
  for (int k=0;k<9;k++)  a9  = fmaf(w9 [d*9+k],  lw[k+2], a9);
  #pragma unroll
  for (int k=0;k<13;k++) a13 = fmaf(w13[d*13+k], lw[k],   a13);
  float* cl = cat + (size_t)bl*768;
  cl[d] = a5;  cl[256+d] = a9;  cl[512+d] = a13;
}

// ---------------- 3 highpass depthwise convs -> cat (as cath) ----------------
__global__ __launch_bounds__(256)
void k_convh(const float* __restrict__ h0,
             const float* __restrict__ w3, const float* __restrict__ wh5,
             const float* __restrict__ w7, float* __restrict__ cat)
{
  const int idx = blockIdx.x*256 + threadIdx.x;
  const int d  = idx & (Dd-1);
  const int bl = idx >> 8;
  const int l  = bl & (Ll-1);
  float hw[7];
  #pragma unroll
  for (int o=0;o<7;o++){
    const int ll = l + o - 3;
    hw[o] = (ll>=0 && ll<Ll) ? h0[(size_t)(bl+o-3)*Dd + d] : 0.0f;
  }
  float c3=0.f, c5=0.f, c7=0.f;
  #pragma unroll
  for (int k=0;k<3;k++)  c3  = fmaf(w3 [d*3+k],  hw[k+2], c3);
  #pragma unroll
  for (int k=0;k<5;k++)  c5  = fmaf(wh5[d*5+k],  hw[k+1], c5);
  #pragma unroll
  for (int k=0;k<7;k++)  c7  = fmaf(w7 [d*7+k],  hw[k],   c7);
  float* ch = cat + (size_t)bl*768;
  ch[d] = c3;  ch[256+d] = c5;  ch[512+d] = c7;
}

// ---------------- causal conv3 + bias + silu on u1 ----------------
__global__ __launch_bounds__(256)
void k_cconv(const float* __restrict__ u1, const float* __restrict__ xbw,
             const float* __restrict__ xbb, float* __restrict__ u)
{
  const int idx = blockIdx.x*256 + threadIdx.x;  // over B*L*H
  const int h  = idx & (Hh-1);
  const int bl = idx >> 9;
  const int l  = bl & (Ll-1);
  float acc = xbb[h];
  #pragma unroll
  for (int k=0;k<3;k++){
    const int ll = l - 2 + k;
    if (ll >= 0) acc = fmaf(xbw[h*3+k], u1[(size_t)(bl-2+k)*Hh + h], acc);
  }
  u[idx] = siluf_(acc);
}

// ---------------- fp32 -> (hi,lo) bf16 planes: dst[0,n)=hi, dst[n,2n)=lo ----------------
__global__ __launch_bounds__(256)
void k_cvt(const float* __restrict__ src, unsigned short* __restrict__ dst, const int n)
{
  const int i = (blockIdx.x*256 + threadIdx.x) << 2;   // n divisible by 1024
  const float4 v = *(const float4*)(src + i);
  float xx[4] = {v.x, v.y, v.z, v.w};
  unsigned short h[4], l[4];
  #pragma unroll
  for (int j=0;j<4;j++){
    h[j] = f2bf(xx[j]);
    l[j] = f2bf(xx[j] - bf2f(h[j]));
  }
  *(ushort4*)(dst + i)     = make_ushort4(h[0],h[1],h[2],h[3]);
  *(ushort4*)(dst + n + i) = make_ushort4(l[0],l[1],l[2],l[3]);
}

// ---------------- shared epilogue ----------------
template<int EPI>
__device__ __forceinline__ float epi_apply(float v, int row, int col,
                                           const float* __restrict__ e0,
                                           const float* __restrict__ e1,
                                           const float* __restrict__ e2, int lde)
{
  if constexpr (EPI==0)      return v;                                       // none (xc)
  else if constexpr (EPI==1) return v + e0[col];                             // +bias (xa)
  else if constexpr (EPI==2) return siluf_(v*(e0[col]*RSQ1PEPS) + e1[col])
                                  + e2[(size_t)row*lde + col];               // fd/fe
  else if constexpr (EPI==3) return siluf_(v*(e0[col]*RSQ1PEPS) + e1[col]);  // ff1
  else if constexpr (EPI==4) return v + 0.5f*(e0[(size_t)row*lde + col]
                                  + e0[(size_t)row*lde + col + 256]);        // ff2 + rr
  else if constexpr (EPI==5) return e1[(size_t)row*lde + col]
                                  * (1.0f + sigmoidf_(v + e0[col]));         // gb -> u1
  else if constexpr (EPI==6) return e1[(size_t)row*lde + col] + v + e0[col]; // gc -> vg
  else if constexpr (EPI==7) return softplusf_(v + e0[col]);                 // xe -> dt
  else                       return v + e0[col] + e1[(size_t)row*lde + col]; // xi (+x)
}

// ---------------- fp32 SIMT GEMM (fallback + xc/xe) ----------------
template<int EPI>
__global__ __launch_bounds__(128)
void k_gemm(const int M, const int N, const int K, const int lda,
            const float* __restrict__ A, const float* __restrict__ W,
            float* __restrict__ C, const int ldc,
            const float* __restrict__ e0, const float* __restrict__ e1,
            const float* __restrict__ e2, const int lde)
{
  __shared__ float As[16][68];
  __shared__ float Bs[16][68];
  const int tid = threadIdx.x;
  const int bm = blockIdx.x << 6;
  const int bn = blockIdx.y << 6;
  const int tx = tid & 15;
  const int ty = tid >> 4;
  const int srow = tid >> 1;
  const int scol = (tid & 1) << 3;

  const float* Aptr = A + (size_t)(bm + srow)*lda + scol;
  const bool bok = (bn + srow) < N;
  const float* Wptr = W + (size_t)(bn + srow)*K + scol;

  float4 a0 = *(const float4*)(Aptr);
  float4 a1 = *(const float4*)(Aptr + 4);
  float4 w0 = make_float4(0.f,0.f,0.f,0.f), w1 = w0;
  if (bok){ w0 = *(const float4*)(Wptr); w1 = *(const float4*)(Wptr + 4); }

  float acc[8][4];
  #pragma unroll
  for (int i=0;i<8;i++)
    #pragma unroll
    for (int j=0;j<4;j++) acc[i][j]=0.0f;

  for (int k0 = 0; k0 < K; k0 += 16){
    __syncthreads();
    As[scol+0][srow]=a0.x; As[scol+1][srow]=a0.y; As[scol+2][srow]=a0.z; As[scol+3][srow]=a0.w;
    As[scol+4][srow]=a1.x; As[scol+5][srow]=a1.y; As[scol+6][srow]=a1.z; As[scol+7][srow]=a1.w;
    Bs[scol+0][srow]=w0.x; Bs[scol+1][srow]=w0.y; Bs[scol+2][srow]=w0.z; Bs[scol+3][srow]=w0.w;
    Bs[scol+4][srow]=w1.x; Bs[scol+5][srow]=w1.y; Bs[scol+6][srow]=w1.z; Bs[scol+7][srow]=w1.w;
    __syncthreads();
    if (k0 + 16 < K){
      a0 = *(const float4*)(Aptr + k0 + 16);
      a1 = *(const float4*)(Aptr + k0 + 20);
      if (bok){
        w0 = *(const float4*)(Wptr + k0 + 16);
        w1 = *(const float4*)(Wptr + k0 + 20);
      }
    }
    #pragma unroll
    for (int kk=0;kk<16;kk++){
      const float4 b4 = *(const float4*)&Bs[kk][tx<<2];
      const float4 aA = *(const float4*)&As[kk][ty<<3];
      const float4 aB = *(const float4*)&As[kk][(ty<<3)+4];
      const float ar[8] = {aA.x,aA.y,aA.z,aA.w,aB.x,aB.y,aB.z,aB.w};
      const float br[4] = {b4.x,b4.y,b4.z,b4.w};
      #pragma unroll
      for (int i=0;i<8;i++)
        #pragma unroll
        for (int j=0;j<4;j++) acc[i][j] = fmaf(ar[i], br[j], acc[i][j]);
    }
  }

  const int col0 = bn + (tx<<2);
  const bool full = (col0 + 3) < N;
  #pragma unroll
  for (int i=0;i<8;i++){
    const int row = bm + (ty<<3) + i;
    float r[4];
    #pragma unroll
    for (int j=0;j<4;j++)
      r[j] = epi_apply<EPI>(acc[i][j], row, col0 + j, e0, e1, e2, lde);
    if (full){
      *(float4*)&C[(size_t)row*ldc + col0] = make_float4(r[0],r[1],r[2],r[3]);
    } else {
      #pragma unroll
      for (int j=0;j<4;j++)
        if (col0 + j < N) C[(size_t)row*ldc + col0 + j] = r[j];
    }
  }
}

// ---------------- split-bf16 MFMA GEMM: C = epi(A @ W^T) ----------------
// M=8192 fixed, lda=K. 128x64 tile, BK=32, 256 thr = 4 waves of 32x64.
// A,W given as bf16 hi/lo planes. C = Ah*Wh + Ah*Wl + Al*Wh (fp32 acc).
template<int EPI>
__global__ __launch_bounds__(256)
void k_mgemm(const int N, const int K,
             const unsigned short* __restrict__ Ahi, const unsigned short* __restrict__ Alo,
             const unsigned short* __restrict__ Whi, const unsigned short* __restrict__ Wlo,
             float* __restrict__ C, const int ldc,
             const float* __restrict__ e0, const float* __restrict__ e1,
             const float* __restrict__ e2, const int lde)
{
  __shared__ unsigned short Ah[128][40];   // 40-row pad: 80B stride -> 2-way banks (free)
  __shared__ unsigned short Al[128][40];
  __shared__ unsigned short Bh[64][40];
  __shared__ unsigned short Bl[64][40];
  const int tid  = threadIdx.x;
  const int bm   = blockIdx.x << 7;
  const int bn   = blockIdx.y << 6;
  const int srow = tid >> 1;             // A staging row 0..127
  const int scol = (tid & 1) << 4;       // 0 or 16 (bf16)
  const int brow = tid >> 2;             // B staging row 0..63
  const int bcol = (tid & 3) << 3;       // 0,8,16,24
  const int wave = tid >> 6;
  const int lane = tid & 63;
  const int m0   = wave << 5;            // wave rows 0,32,64,96
  const int fr   = lane & 15;            // frag row/col
  const int fgo  = (lane >> 4) << 3;     // frag k-offset 0,8,16,24

  const unsigned short* Agh = Ahi + (size_t)(bm + srow)*K + scol;
  const unsigned short* Agl = Alo + (size_t)(bm + srow)*K + scol;
  const unsigned short* Wgh = Whi + (size_t)(bn + brow)*K + bcol;
  const unsigned short* Wgl = Wlo + (size_t)(bn + brow)*K + bcol;

  f4_t acc[2][4];
  #pragma unroll
  for (int mi=0;mi<2;mi++)
    #pragma unroll
    for (int ni=0;ni<4;ni++)
      #pragma unroll
      for (int e=0;e<4;e++) acc[mi][ni][e] = 0.0f;

  for (int k0 = 0; k0 < K; k0 += 32){
    const uint4 ah0 = *(const uint4*)(Agh + k0);
    const uint4 ah1 = *(const uint4*)(Agh + k0 + 8);
    const uint4 al0 = *(const uint4*)(Agl + k0);
    const uint4 al1 = *(const uint4*)(Agl + k0 + 8);
    const uint4 wh  = *(const uint4*)(Wgh + k0);
    const uint4 wl  = *(const uint4*)(Wgl + k0);
    __syncthreads();
    *(uint4*)&Ah[srow][scol]   = ah0;
    *(uint4*)&Ah[srow][scol+8] = ah1;
    *(uint4*)&Al[srow][scol]   = al0;
    *(uint4*)&Al[srow][scol+8] = al1;
    *(uint4*)&Bh[brow][bcol]   = wh;
    *(uint4*)&Bl[brow][bcol]   = wl;
    __syncthreads();
    bf8_t amh[2], aml[2], bnh[4], bnl[4];
    #pragma unroll
    for (int mi=0;mi<2;mi++){
      amh[mi] = *(const bf8_t*)&Ah[m0 + (mi<<4) + fr][fgo];
      aml[mi] = *(const bf8_t*)&Al[m0 + (mi<<4) + fr][fgo];
    }
    #pragma unroll
    for (int ni=0;ni<4;ni++){
      bnh[ni] = *(const bf8_t*)&Bh[(ni<<4) + fr][fgo];
      bnl[ni] = *(const bf8_t*)&Bl[(ni<<4) + fr][fgo];
    }
    #pragma unroll
    for (int mi=0;mi<2;mi++)
      #pragma unroll
      for (int ni=0;ni<4;ni++){
        acc[mi][ni] = __builtin_amdgcn_mfma_f32_16x16x32_bf16(amh[mi], bnh[ni], acc[mi][ni], 0,0,0);
        acc[mi][ni] = __builtin_amdgcn_mfma_f32_16x16x32_bf16(amh[mi], bnl[ni], acc[mi][ni], 0,0,0);
        acc[mi][ni] = __builtin_amdgcn_mfma_f32_16x16x32_bf16(aml[mi], bnh[ni], acc[mi][ni], 0,0,0);
      }
  }

  // C/D layout (HW-verified): col = lane&15, row = (lane>>4)*4 + reg
  const int rbase = bm + m0 + ((lane>>4)<<2);
  #pragma unroll
  for (int mi=0;mi<2;mi++){
    #pragma unroll
    for (int ni=0;ni<4;ni++){
      const int col = bn + (ni<<4) + fr;
      #pragma unroll
      for (int j=0;j<4;j++){
        const int row = rbase + (mi<<4) + j;
        C[(size_t)row*ldc + col] = epi_apply<EPI>(acc[mi][ni][j], row, col, e0, e1, e2, lde);
      }
    }
  }
}

// ---------------- SSM scan: one wave per (b,h) chain ----------------
__global__ __launch_bounds__(256)
void k_scan(const float* __restrict__ dt, const float* __restrict__ u,
            const float* __restrict__ zc, const float* __restrict__ xf,
            const float* __restrict__ xg, const float* __restrict__ vg,
            float* __restrict__ y)
{
  const int wid  = blockIdx.x*4 + (threadIdx.x>>6);
  const int lane = threadIdx.x & 63;
  const int b = wid >> 9;
  const int h = wid & (Hh-1);
  float a[16];
  #pragma unroll
  for (int s=0;s<16;s++) a[s] = -expf(xf[h*16+s]);
  const int CH = Ll/64;
  const size_t rowbase = (size_t)b*Ll + lane*CH;
  float P[16], st[16];
  #pragma unroll
  for (int s=0;s<16;s++){ P[s]=1.0f; st[s]=0.0f; }
  for (int j=0;j<CH;j++){
    const size_t row = rowbase + j;
    const float dtv = dt[row*Hh + h];
    const float uv  = u [row*Hh + h];
    const float du  = dtv*uv;
    const float* z48 = zc + row*48;
    #pragma unroll
    for (int s=0;s<16;s++){
      const float aa = expf(dtv*a[s]);
      st[s] = fmaf(aa, st[s], du*z48[16+s]);
      P[s] *= aa;
    }
  }
  #pragma unroll
  for (int dd=1; dd<64; dd<<=1){
    #pragma unroll
    for (int s=0;s<16;s++){
      const float Po = __shfl_up(P[s],  dd, 64);
      const float Bo = __shfl_up(st[s], dd, 64);
      if (lane >= dd){ st[s] = fmaf(P[s], Bo, st[s]); P[s] *= Po; }
    }
  }
  float init[16];
  #pragma unroll
  for (int s=0;s<16;s++){
    const float e = __shfl_up(st[s], 1, 64);
    init[s] = (lane==0) ? 0.0f : e;
  }
  const float xgh = xg[h];
  #pragma unroll
  for (int s=0;s<16;s++) st[s] = init[s];
  for (int j=0;j<CH;j++){
    const size_t row = rowbase + j;
    const float dtv = dt[row*Hh + h];
    const float uv  = u [row*Hh + h];
    const float du  = dtv*uv;
    const float* z48 = zc + row*48;
    float ys = 0.0f;
    #pragma unroll
    for (int s=0;s<16;s++){
      const float aa = expf(dtv*a[s]);
      st[s] = fmaf(aa, st[s], du*z48[16+s]);
      ys = fmaf(st[s], z48[32+s], ys);
    }
    const float vgv = vg[row*Hh + h];
    const float yv = (ys + uv*xgh) * (vgv / (1.0f + expf(-vgv)));
    y[row*Hh + h] = yv;
  }
}

extern "C" void kernel_launch(void* const* d_in, const int* in_sizes, int n_in,
                              void* d_out, int out_size, void* d_ws, size_t ws_size,
                              hipStream_t stream)
{
  const float* x      = (const float*)d_in[0];
  const float* ln1_g  = (const float*)d_in[1];
  const float* ln1_b  = (const float*)d_in[2];
  const float* favg_w = (const float*)d_in[3];
  const float* lk5_w  = (const float*)d_in[4];
  const float* lk9_w  = (const float*)d_in[5];
  const float* lk13_w = (const float*)d_in[6];
  const float* hk3_w  = (const float*)d_in[7];
  const float* hk5_w  = (const float*)d_in[8];
  const float* hk7_w  = (const float*)d_in[9];
  const float* fd_w   = (const float*)d_in[10];
  const float* fd_bn_g= (const float*)d_in[11];
  const float* fd_bn_b= (const float*)d_in[12];
  const float* fe_w   = (const float*)d_in[13];
  const float* fe_bn_g= (const float*)d_in[14];
  const float* fe_bn_b= (const float*)d_in[15];
  const float* ff1_w  = (const float*)d_in[16];
  const float* ff_bn_g= (const float*)d_in[17];
  const float* ff_bn_b= (const float*)d_in[18];
  const float* ff2_w  = (const float*)d_in[19];
  const float* fln_g  = (const float*)d_in[20];
  const float* fln_b  = (const float*)d_in[21];
  const float* xa_w   = (const float*)d_in[22];
  const float* xa_b   = (const float*)d_in[23];
  const float* xb_w   = (const float*)d_in[24];
  const float* xb_b   = (const float*)d_in[25];
  const float* xc_w   = (const float*)d_in[26];
  const float* xe_w   = (const float*)d_in[27];
  const float* xe_b   = (const float*)d_in[28];
  const float* xf     = (const float*)d_in[29];
  const float* xg     = (const float*)d_in[30];
  const float* xi_w   = (const float*)d_in[31];
  const float* xi_b   = (const float*)d_in[32];
  const float* gln_g  = (const float*)d_in[33];
  const float* gln_b  = (const float*)d_in[34];
  const float* gb_w   = (const float*)d_in[35];
  const float* gb_b   = (const float*)d_in[36];
  const float* gc_w   = (const float*)d_in[37];
  const float* gc_b   = (const float*)d_in[38];
  float* out = (float*)d_out;

  if (ws_size < WS_NEED_BYTES) return;           // can't run at all
  const bool MF = (ws_size >= WS_NEED2_BYTES);   // MFMA path needs plane arena

  float* ws = (float*)d_ws;
  float* z    = out;              // d_out doubles as z-scratch (dead before step 16)
  float* l0   = ws + OFF_L0;
  float* h0   = ws + OFF_H0;
  float* cat  = ws + OFF_CAT;
  float* lh   = ws + OFF_LH;
  float* t    = ws + OFF_T;
  float* cc   = ws + OFF_CC;
  float* ctxn = ws + OFF_CTXN;
  float* zu   = ws + OFF_ZU;
  float* zv   = ws + OFF_ZV;
  float* u    = ws + OFF_U;
  float* zcb  = ws + OFF_ZC;
  float* dt   = ws + OFF_DT;
  float* y    = ws + OFF_Y;

  // bf16 plane arena (above fp32 arena)
  unsigned short* bfp = (unsigned short*)(ws + 16777216u);
  unsigned short* pfd  = bfp;             // 2*196608
  unsigned short* pfe  = bfp + 393216u;   // 2*196608
  unsigned short* pff1 = bfp + 786432u;   // 2*262144
  unsigned short* pff2 = bfp + 1310720u;  // 2*131072
  unsigned short* pxa  = bfp + 1572864u;  // 2*262144
  unsigned short* pgb  = bfp + 2097152u;  // 2*131072
  unsigned short* pgc  = bfp + 2359296u;  // 2*131072
  unsigned short* pxi  = bfp + 2621440u;  // 2*131072
  unsigned short* pact = bfp + 2883584u;  // 2*6291456 (activation slot, serial reuse)

  const dim3 thr(256);
  const dim3 gthr(128);

  if (MF){  // weight hi/lo planes (cheap, once per call)
    k_cvt<<<dim3(192),thr,0,stream>>>(fd_w,  pfd,  196608);
    k_cvt<<<dim3(192),thr,0,stream>>>(fe_w,  pfe,  196608);
    k_cvt<<<dim3(256),thr,0,stream>>>(ff1_w, pff1, 262144);
    k_cvt<<<dim3(128),thr,0,stream>>>(ff2_w, pff2, 131072);
    k_cvt<<<dim3(256),thr,0,stream>>>(xa_w,  pxa,  262144);
    k_cvt<<<dim3(128),thr,0,stream>>>(gb_w,  pgb,  131072);
    k_cvt<<<dim3(128),thr,0,stream>>>(gc_w,  pgc,  131072);
    k_cvt<<<dim3(128),thr,0,stream>>>(xi_w,  pxi,  131072);
  }

  // 1) z = LN(x)
  k_ln1<<<dim3(BLrows/4), thr, 0, stream>>>(x, ln1_g, ln1_b, z);
  // 2) l0 = avg9(z), h0 = z - l0
  k_avg<<<dim3(BLrows*Dd/256), thr, 0, stream>>>(z, favg_w, l0, h0);
  // 3a) lowpass convs -> cat
  k_convl<<<dim3(BLrows*Dd/256), thr, 0, stream>>>(l0, lk5_w, lk9_w, lk13_w, cat);
  // 4) l1 -> lh[:, :256]
  if (MF){
    k_cvt<<<dim3(6144),thr,0,stream>>>(cat, pact, 6291456);
    k_mgemm<2><<<dim3(64,4), thr, 0, stream>>>(256,768, pact, pact+6291456u,
                                               pfd, pfd+196608u, lh,512, fd_bn_g, fd_bn_b, l0,256);
  } else {
    k_gemm<2><<<dim3(128,4), gthr, 0, stream>>>(BLrows,256,768,768, cat, fd_w,
                                                lh, 512, fd_bn_g, fd_bn_b, l0, 256);
  }
  // 3b) highpass convs -> cat
  k_convh<<<dim3(BLrows*Dd/256), thr, 0, stream>>>(h0, hk3_w, hk5_w, hk7_w, cat);
  // 5) h1 -> lh[:, 256:]
  if (MF){
    k_cvt<<<dim3(6144),thr,0,stream>>>(cat, pact, 6291456);
    k_mgemm<2><<<dim3(64,4), thr, 0, stream>>>(256,768, pact, pact+6291456u,
                                               pfe, pfe+196608u, lh+256,512, fe_bn_g, fe_bn_b, h0,256);
  } else {
    k_gemm<2><<<dim3(128,4), gthr, 0, stream>>>(BLrows,256,768,768, cat, fe_w,
                                                lh+256, 512, fe_bn_g, fe_bn_b, h0, 256);
  }
  // 6) t = silu(bn(lh@ff1^T))
  if (MF){
    k_cvt<<<dim3(4096),thr,0,stream>>>(lh, pact, 4194304);
    k_mgemm<3><<<dim3(64,8), thr, 0, stream>>>(512,512, pact, pact+4194304u,
                                               pff1, pff1+262144u, t,512, ff_bn_g, ff_bn_b, nullptr,0);
  } else {
    k_gemm<3><<<dim3(128,8), gthr, 0, stream>>>(BLrows,512,512,512, lh, ff1_w,
                                                t, 512, ff_bn_g, ff_bn_b, nullptr, 0);
  }
  // 7) cc = t@ff2^T + 0.5*(l1+h1)
  if (MF){
    k_cvt<<<dim3(4096),thr,0,stream>>>(t, pact, 4194304);
    k_mgemm<4><<<dim3(64,4), thr, 0, stream>>>(256,512, pact, pact+4194304u,
                                               pff2, pff2+131072u, cc,256, lh, nullptr, nullptr,512);
  } else {
    k_gemm<4><<<dim3(128,4), gthr, 0, stream>>>(BLrows,256,512,512, t, ff2_w,
                                                cc, 256, lh, nullptr, nullptr, 512);
  }
  // 8) ctxn = LN(LN(cc, fln), gln)
  k_dln<<<dim3(BLrows/4), thr, 0, stream>>>(cc, fln_g, fln_b, gln_g, gln_b, ctxn);
  // 9) zu/zv = z@xa^T halves + bias
  if (MF){
    k_cvt<<<dim3(2048),thr,0,stream>>>(z, pact, 2097152);
    k_mgemm<1><<<dim3(64,8), thr, 0, stream>>>(512,256, pact, pact+2097152u,
                                               pxa, pxa+262144u, zu,512, xa_b, nullptr, nullptr,0);
    k_mgemm<1><<<dim3(64,8), thr, 0, stream>>>(512,256, pact, pact+2097152u,
                                               pxa+131072u, pxa+393216u, zv,512, xa_b+512, nullptr, nullptr,0);
  } else {
    k_gemm<1><<<dim3(128,8), gthr, 0, stream>>>(BLrows,512,256,256, z, xa_w,
                                                zu, 512, xa_b, nullptr, nullptr, 0);
    k_gemm<1><<<dim3(128,8), gthr, 0, stream>>>(BLrows,512,256,256, z, xa_w + 512*256,
                                                zv, 512, xa_b + 512, nullptr, nullptr, 0);
  }
  // 10/11) gating GEMMs (in-place epilogues over zu/zv)
  if (MF){
    k_cvt<<<dim3(2048),thr,0,stream>>>(ctxn, pact, 2097152);
    k_mgemm<5><<<dim3(64,8), thr, 0, stream>>>(512,256, pact, pact+2097152u,
                                               pgb, pgb+131072u, zu,512, gb_b, zu, nullptr,512);
    k_mgemm<6><<<dim3(64,8), thr, 0, stream>>>(512,256, pact, pact+2097152u,
                                               pgc, pgc+131072u, zv,512, gc_b, zv, nullptr,512);
  } else {
    k_gemm<5><<<dim3(128,8), gthr, 0, stream>>>(BLrows,512,256,256, ctxn, gb_w,
                                                zu, 512, gb_b, zu, nullptr, 512);
    k_gemm<6><<<dim3(128,8), gthr, 0, stream>>>(BLrows,512,256,256, ctxn, gc_w,
                                                zv, 512, gc_b, zv, nullptr, 512);
  }
  // 12) u = silu(causal_conv3(u1) + xb_b)
  k_cconv<<<dim3(BLrows*Hh/256), thr, 0, stream>>>(zu, xb_w, xb_b, u);
  // 13) zc = u@xc^T (N=48, fp32 SIMT)
  k_gemm<0><<<dim3(128,1), gthr, 0, stream>>>(BLrows,48,512,512, u, xc_w,
                                              zcb, 48, nullptr, nullptr, nullptr, 0);
  // 14) dt = softplus(zc[:, :16]@xe^T + xe_b) (K=16, fp32 SIMT)
  k_gemm<7><<<dim3(128,8), gthr, 0, stream>>>(BLrows,512,16,48, zcb, xe_w,
                                              dt, 512, xe_b, nullptr, nullptr, 0);
  // 15) scan
  k_scan<<<dim3(512), thr, 0, stream>>>(dt, u, zcb, xf, xg, zv, y);
  // 16) out = y@xi^T + xi_b + x
  if (MF){
    k_cvt<<<dim3(4096),thr,0,stream>>>(y, pact, 4194304);
    k_mgemm<8><<<dim3(64,4), thr, 0, stream>>>(256,512, pact, pact+4194304u,
                                               pxi, pxi+131072u, out,256, xi_b, x, nullptr,256);
  } else {
    k_gemm<8><<<dim3(128,4), gthr, 0, stream>>>(BLrows,256,512,512, y, xi_w,
                                                out, 256, xi_b, x, nullptr, 256);
  }
}